// Round 10
// baseline (32.438 us; speedup 1.0000x reference)
//
#include <hip/hip_runtime.h>

// BackprojectDepth: out[b, 0:3, k] = depth[b, idx] * (inv_K[b,:3,:3] @ [gx, gy, 1])
//                   out[b, 3, k]   = 1.0
// idx = top_k_indices[b,k], gx = idx % W, gy = idx / W.
// pix_coords input is a meshgrid -> recomputed arithmetically, never read.
//
// Round 10: exact R3 structure (best: 18.3us; 2048 blocks, ILP=4, XCD remap,
// nt idx load, nt out stores) + ONE change: depth gathers are nontemporal
// (`nt` flag: no L1 allocation / evict-first; still L2/L3 cached — unlike
// R6's sc0 coherence scope which killed L2). Theory: random 4B gathers get
// ~0% L1 hits but each occupies an L1 MSHR for the full L2/L3 round trip;
// measured 5.4 cyc/line-transaction/CU matches an MSHR-limited rate.
// R8 evidence: FETCH_SIZE only 21MB -> gathers are L3-warm, not HBM-bound.

#define BB 16
#define HH 384
#define WW 1280
#define HWSZ (HH * WW)
#define KK 131072
#define NXCD 8
#define BLOCKS_PER_BATCH (KK / (256 * 4))    // 128
#define TOTAL_BLOCKS (BB * BLOCKS_PER_BATCH) // 2048

typedef float v4f __attribute__((ext_vector_type(4)));
typedef int   v4i __attribute__((ext_vector_type(4)));

__global__ __launch_bounds__(256) void backproject_kernel(
    const float* __restrict__ depth,   // B*HW
    const float* __restrict__ invK,    // B*16
    const int*   __restrict__ topk,    // B*K
    float*       __restrict__ out)     // B*4*K
{
    // Phys block i -> XCD i%8; XCD x serves batches 2x,2x+1 (3.75MB < 4MB L2).
    const int xcd  = blockIdx.x & (NXCD - 1);
    const int slot = blockIdx.x >> 3;                       // 0..255
    const int logical = xcd * (TOTAL_BLOCKS / NXCD) + slot; // 0..2047
    const int b   = logical >> 7;                           // batch
    const int blk = logical & 127;                          // block within batch
    const int k0  = blk * 1024 + threadIdx.x * 4;

    const float* __restrict__ M = invK + b * 16;
    const float m00 = M[0], m01 = M[1], m02 = M[2];
    const float m10 = M[4], m11 = M[5], m12 = M[6];
    const float m20 = M[8], m21 = M[9], m22 = M[10];

    const v4i idx4 = __builtin_nontemporal_load(
        reinterpret_cast<const v4i*>(topk + b * KK + k0));
    const float* __restrict__ db = depth + b * HWSZ;

    const int idxs[4] = {idx4[0], idx4[1], idx4[2], idx4[3]};
    float d[4];
#pragma unroll
    for (int j = 0; j < 4; ++j)
        d[j] = __builtin_nontemporal_load(db + idxs[j]);   // nt gather: no L1 alloc

    float ox[4], oy[4], oz[4];
#pragma unroll
    for (int j = 0; j < 4; ++j) {
        const int idx = idxs[j];
        const float gx = (float)(idx % WW);
        const float gy = (float)(idx / WW);
        ox[j] = d[j] * fmaf(m00, gx, fmaf(m01, gy, m02));
        oy[j] = d[j] * fmaf(m10, gx, fmaf(m11, gy, m12));
        oz[j] = d[j] * fmaf(m20, gx, fmaf(m21, gy, m22));
    }

    float* __restrict__ ob = out + (size_t)b * 4 * KK + k0;
    v4f vx = {ox[0], ox[1], ox[2], ox[3]};
    v4f vy = {oy[0], oy[1], oy[2], oy[3]};
    v4f vz = {oz[0], oz[1], oz[2], oz[3]};
    v4f vw = {1.f, 1.f, 1.f, 1.f};
    __builtin_nontemporal_store(vx, reinterpret_cast<v4f*>(ob + 0 * KK));
    __builtin_nontemporal_store(vy, reinterpret_cast<v4f*>(ob + 1 * KK));
    __builtin_nontemporal_store(vz, reinterpret_cast<v4f*>(ob + 2 * KK));
    __builtin_nontemporal_store(vw, reinterpret_cast<v4f*>(ob + 3 * KK));
}

extern "C" void kernel_launch(void* const* d_in, const int* in_sizes, int n_in,
                              void* d_out, int out_size, void* d_ws, size_t ws_size,
                              hipStream_t stream) {
    const float* depth = (const float*)d_in[0];     // (B,1,H,W) f32
    const float* invK  = (const float*)d_in[1];     // (B,4,4) f32
    // d_in[2] = pix_coords — intentionally unused (recomputed from index)
    const int*   topk  = (const int*)d_in[3];       // (B,K) i32
    float* out = (float*)d_out;                     // (B,4,K) f32

    backproject_kernel<<<TOTAL_BLOCKS, 256, 0, stream>>>(depth, invK, topk, out);
}

// Round 11
// 21.123 us; speedup vs baseline: 1.5356x; 1.5356x over previous
//
#include <hip/hip_runtime.h>

// BackprojectDepth: out[b, 0:3, k] = depth[b, idx] * (inv_K[b,:3,:3] @ [gx, gy, 1])
//                   out[b, 3, k]   = 1.0
// idx = top_k_indices[b,k], gx = idx % W, gy = idx / W.
// pix_coords input is a meshgrid -> recomputed arithmetically, never read.
//
// Round 11: decompose the R1->R3 bundle. Exact R3 structure (2048 blocks,
// ILP=4, XCD remap, nt idx load, plain gathers) with ONE change: output
// stores are PLAIN (write-back) instead of nontemporal. R10 showed nt loads
// take a pathological L2-bypass path on gfx950; testing whether nt stores
// are similarly slow (win expected) or were protecting L2 from the output
// stream (regress expected). Discriminates with one probe.

#define BB 16
#define HH 384
#define WW 1280
#define HWSZ (HH * WW)
#define KK 131072
#define NXCD 8
#define BLOCKS_PER_BATCH (KK / (256 * 4))    // 128
#define TOTAL_BLOCKS (BB * BLOCKS_PER_BATCH) // 2048

typedef float v4f __attribute__((ext_vector_type(4)));
typedef int   v4i __attribute__((ext_vector_type(4)));

__global__ __launch_bounds__(256) void backproject_kernel(
    const float* __restrict__ depth,   // B*HW
    const float* __restrict__ invK,    // B*16
    const int*   __restrict__ topk,    // B*K
    float*       __restrict__ out)     // B*4*K
{
    // Phys block i -> XCD i%8; XCD x serves batches 2x,2x+1 (3.75MB < 4MB L2).
    const int xcd  = blockIdx.x & (NXCD - 1);
    const int slot = blockIdx.x >> 3;                       // 0..255
    const int logical = xcd * (TOTAL_BLOCKS / NXCD) + slot; // 0..2047
    const int b   = logical >> 7;                           // batch
    const int blk = logical & 127;                          // block within batch
    const int k0  = blk * 1024 + threadIdx.x * 4;

    const float* __restrict__ M = invK + b * 16;
    const float m00 = M[0], m01 = M[1], m02 = M[2];
    const float m10 = M[4], m11 = M[5], m12 = M[6];
    const float m20 = M[8], m21 = M[9], m22 = M[10];

    const v4i idx4 = __builtin_nontemporal_load(
        reinterpret_cast<const v4i*>(topk + b * KK + k0));
    const float* __restrict__ db = depth + b * HWSZ;

    const int idxs[4] = {idx4[0], idx4[1], idx4[2], idx4[3]};
    float d[4];
#pragma unroll
    for (int j = 0; j < 4; ++j) d[j] = db[idxs[j]];   // plain gathers (L2-cached)

    float ox[4], oy[4], oz[4];
#pragma unroll
    for (int j = 0; j < 4; ++j) {
        const int idx = idxs[j];
        const float gx = (float)(idx % WW);
        const float gy = (float)(idx / WW);
        ox[j] = d[j] * fmaf(m00, gx, fmaf(m01, gy, m02));
        oy[j] = d[j] * fmaf(m10, gx, fmaf(m11, gy, m12));
        oz[j] = d[j] * fmaf(m20, gx, fmaf(m21, gy, m22));
    }

    float* __restrict__ ob = out + (size_t)b * 4 * KK + k0;
    *reinterpret_cast<v4f*>(ob + 0 * KK) = (v4f){ox[0], ox[1], ox[2], ox[3]};
    *reinterpret_cast<v4f*>(ob + 1 * KK) = (v4f){oy[0], oy[1], oy[2], oy[3]};
    *reinterpret_cast<v4f*>(ob + 2 * KK) = (v4f){oz[0], oz[1], oz[2], oz[3]};
    *reinterpret_cast<v4f*>(ob + 3 * KK) = (v4f){1.f, 1.f, 1.f, 1.f};
}

extern "C" void kernel_launch(void* const* d_in, const int* in_sizes, int n_in,
                              void* d_out, int out_size, void* d_ws, size_t ws_size,
                              hipStream_t stream) {
    const float* depth = (const float*)d_in[0];     // (B,1,H,W) f32
    const float* invK  = (const float*)d_in[1];     // (B,4,4) f32
    // d_in[2] = pix_coords — intentionally unused (recomputed from index)
    const int*   topk  = (const int*)d_in[3];       // (B,K) i32
    float* out = (float*)d_out;                     // (B,4,K) f32

    backproject_kernel<<<TOTAL_BLOCKS, 256, 0, stream>>>(depth, invK, topk, out);
}